// Round 3
// baseline (440.638 us; speedup 1.0000x reference)
//
#include <hip/hip_runtime.h>

// Generalized Lotka-Volterra, RK4, D=64, batch 2048, 255 steps,
// trajectory out (batch, 256, 64) fp32.
//
// Mapping: one 64-lane wave per batch element; lane l = (g,p), g=l>>4, p=l&15
// owns component l and a pre-permuted copy of row l of A in 64 VGPRs.
// The matvec sum_j A[l][j] x[j] is decomposed into 4 phases (row-group xor t)
// x 16 masks (in-row xor m):   j = 16*(g^t) + (p^m).
//  - phase states xt_t = x shuffled by xor{16,32,48}: DS pipe (swizzle/bpermute)
//  - masks {1,2,3}: DPP quad_perm, {7}: row_half_mirror, {15}: row_mirror
//    (all self-inverse -> no direction-convention risk), {0}: plain,
//    {4,5,6,8..14}: ds_swizzle xor (DS pipe, zero VALU cost)
// A is loaded pre-permuted so every fmac pairs the right A element.
// __launch_bounds__(256,2): 256-VGPR budget so A stays register-resident
// (round-2 failure mode: default heuristic capped at 48 VGPRs and
// rematerialized A loads every feval).

constexpr int D   = 64;   // state dimension == wavefront size
constexpr int NT  = 256;  // trajectory length (255 RK4 steps)
constexpr int WPB = 4;    // waves (= batch elements) per block

// DPP-permuted read of v (compiler-visible: hazards + scheduling handled).
#define DPPF(v, ctrl) \
    __int_as_float(__builtin_amdgcn_update_dpp(0, __float_as_int(v), (ctrl), 0xF, 0xF, true))
// ds_swizzle BitMode: offset = (xor<<10)|(or<<5)|and, and=0x1F keeps all lanes.
#define SWZ(v, xm) \
    __int_as_float(__builtin_amdgcn_ds_swizzle(__float_as_int(v), (((xm) << 10) | 0x1F)))

#define QP_XOR1 0xB1   // quad_perm:[1,0,3,2]
#define QP_XOR2 0x4E   // quad_perm:[2,3,0,1]
#define QP_XOR3 0x1B   // quad_perm:[3,2,1,0]
#define ROW_MIRROR      0x140  // p -> p^15
#define ROW_HALF_MIRROR 0x141  // p -> p^7

// One phase: accumulate masks m=0..15 of phase state XT against A-regs AT[16].
// 6 VALU fmacs (1 plain + 5 DPP-sourced) + 10 DS-swizzle-sourced fmacs.
#define PHASE(XT, AT)                                                   \
    do {                                                                \
        const float xp = (XT);                                          \
        const float s4  = SWZ(xp, 4),  s5  = SWZ(xp, 5);                \
        const float s6  = SWZ(xp, 6),  s8  = SWZ(xp, 8);                \
        const float s9  = SWZ(xp, 9),  s10 = SWZ(xp, 10);               \
        const float s11 = SWZ(xp, 11), s12 = SWZ(xp, 12);               \
        const float s13 = SWZ(xp, 13), s14 = SWZ(xp, 14);               \
        acc0 += xp * AT[0];                                             \
        acc1 += DPPF(xp, QP_XOR1) * AT[1];                              \
        acc2 += DPPF(xp, QP_XOR2) * AT[2];                              \
        acc3 += DPPF(xp, QP_XOR3) * AT[3];                              \
        acc0 += s4 * AT[4];                                             \
        acc1 += s5 * AT[5];                                             \
        acc2 += s6 * AT[6];                                             \
        acc3 += DPPF(xp, ROW_HALF_MIRROR) * AT[7];                      \
        acc0 += s8  * AT[8];                                            \
        acc1 += s9  * AT[9];                                            \
        acc2 += s10 * AT[10];                                           \
        acc3 += s11 * AT[11];                                           \
        acc0 += s12 * AT[12];                                           \
        acc1 += s13 * AT[13];                                           \
        acc2 += s14 * AT[14];                                           \
        acc3 += DPPF(xp, ROW_MIRROR) * AT[15];                          \
    } while (0)

// f(xt) = xt * (r + A @ xt), wave-cooperative.
#define FEVAL(XT, RES)                                                  \
    do {                                                                \
        const float xt0 = (XT);                                         \
        const float xt2 = __shfl_xor(xt0, 32, 64);  /* g^2 (bpermute) */\
        const float xt1 = SWZ(xt0, 16);             /* g^1 */           \
        const float xt3 = SWZ(xt2, 16);             /* g^3 */           \
        float acc0 = ri, acc1 = 0.f, acc2 = 0.f, acc3 = 0.f;            \
        PHASE(xt0, am[0]);                                              \
        PHASE(xt1, am[1]);                                              \
        PHASE(xt2, am[2]);                                              \
        PHASE(xt3, am[3]);                                              \
        RES = xt0 * ((acc0 + acc1) + (acc2 + acc3));                    \
    } while (0)

__global__ __launch_bounds__(WPB * 64, 2)
void glv_rk4_kernel(const float* __restrict__ x0,
                    const float* __restrict__ r,
                    const float* __restrict__ A,
                    const float* __restrict__ tgrid,
                    float* __restrict__ out)
{
    const int lane = threadIdx.x & 63;
    const int wid  = threadIdx.x >> 6;
    const int b    = blockIdx.x * WPB + wid;   // batch element for this wave
    const int g    = lane >> 4;
    const int p    = lane & 15;

    // Pre-permuted row `lane` of A into 64 registers (constant indices ->
    // SROA-promoted; one-time uncoalesced loads, L2-resident, amortized).
    float am[4][16];
#pragma unroll
    for (int t = 0; t < 4; ++t)
#pragma unroll
        for (int m = 0; m < 16; ++m)
            am[t][m] = A[lane * D + 16 * (g ^ t) + (p ^ m)];

    const float ri = r[lane];
    const float dt = tgrid[1] - tgrid[0];
    const float h2 = 0.5f * dt;
    const float h6 = dt * (1.0f / 6.0f);

    float x = x0[(size_t)b * D + lane];

    float* o = out + (size_t)b * NT * D + lane;
    *o = x; o += D;                            // t = 0 is x0

    for (int t = 1; t < NT; ++t) {
        float k1, k2, k3, k4;
        FEVAL(x, k1);
        FEVAL(fmaf(h2, k1, x), k2);
        FEVAL(fmaf(h2, k2, x), k3);
        FEVAL(fmaf(dt, k3, x), k4);
        x = fmaf(h6, (k1 + k4) + 2.0f * (k2 + k3), x);
        *o = x; o += D;                        // coalesced 256 B/wave store
    }
}

extern "C" void kernel_launch(void* const* d_in, const int* in_sizes, int n_in,
                              void* d_out, int out_size, void* d_ws, size_t ws_size,
                              hipStream_t stream) {
    const float* x0    = (const float*)d_in[0];
    const float* r     = (const float*)d_in[1];
    const float* A     = (const float*)d_in[2];
    const float* tgrid = (const float*)d_in[3];
    float* out         = (float*)d_out;

    const int batch = in_sizes[0] / D;          // 2048
    dim3 grid(batch / WPB);                     // 512 blocks
    dim3 block(WPB * 64);                       // 256 threads = 4 waves

    glv_rk4_kernel<<<grid, block, 0, stream>>>(x0, r, A, tgrid, out);
}

// Round 4
// 414.927 us; speedup vs baseline: 1.0620x; 1.0620x over previous
//
#include <hip/hip_runtime.h>

// Generalized Lotka-Volterra, RK4, D=64, batch 2048, 255 steps,
// trajectory out (batch, 256, 64) fp32.
//
// Mapping: one 64-lane wave per batch element; lane i owns component i and
// row i of A in 64 VGPRs. Stage-state broadcast via wave-private LDS buffer:
// 1 ds_write_b32 + lgkmcnt(0) + 16 uniform-address ds_read_b128 (hardware
// broadcast, conflict-free). Lowest VALU issue count of the tried variants
// (~68/feval vs 132 for readlane, 111 for ds_swizzle).
//
// THE fix this round: pin a[64] with `asm volatile("" : "+v")` after the
// load. Rounds 1-3 all show VGPR_Count 48-60 => the compiler sank the
// loop-invariant A loads into the loop (re-fetch per feval + vmcnt stalls).
// A volatile asm executes exactly once, so the loads can't sink past it and
// the 64 values must stay VGPR-resident across the time loop.
// __launch_bounds__(256, 2): 2 waves/SIMD structural occupancy (2048 waves
// total), giving the allocator a 256-VGPR budget so the pin can't spill.

constexpr int D   = 64;   // state dimension == wavefront size
constexpr int NT  = 256;  // trajectory length (255 RK4 steps)
constexpr int WPB = 4;    // waves (= batch elements) per block

// f(xt) = xt * (r + A @ xt), wave-cooperative via LDS broadcast.
#define FEVAL(XT, BUF, RES)                                                   \
    do {                                                                      \
        const float xt_ = (XT);                                               \
        (BUF)[lane] = xt_;                                  /* ds_write_b32 */\
        asm volatile("s_waitcnt lgkmcnt(0)" ::: "memory");  /* wave-sync   */ \
        float acc0 = ri, acc1 = 0.f, acc2 = 0.f, acc3 = 0.f;                  \
        _Pragma("unroll")                                                     \
        for (int j = 0; j < D; j += 16) {                                     \
            const float4 v0 = *reinterpret_cast<const float4*>((BUF) + j);    \
            const float4 v1 = *reinterpret_cast<const float4*>((BUF) + j + 4);\
            const float4 v2 = *reinterpret_cast<const float4*>((BUF) + j + 8);\
            const float4 v3 = *reinterpret_cast<const float4*>((BUF) + j +12);\
            acc0 = fmaf(a[j +  0], v0.x, acc0);                               \
            acc1 = fmaf(a[j +  1], v0.y, acc1);                               \
            acc2 = fmaf(a[j +  2], v0.z, acc2);                               \
            acc3 = fmaf(a[j +  3], v0.w, acc3);                               \
            acc0 = fmaf(a[j +  4], v1.x, acc0);                               \
            acc1 = fmaf(a[j +  5], v1.y, acc1);                               \
            acc2 = fmaf(a[j +  6], v1.z, acc2);                               \
            acc3 = fmaf(a[j +  7], v1.w, acc3);                               \
            acc0 = fmaf(a[j +  8], v2.x, acc0);                               \
            acc1 = fmaf(a[j +  9], v2.y, acc1);                               \
            acc2 = fmaf(a[j + 10], v2.z, acc2);                               \
            acc3 = fmaf(a[j + 11], v2.w, acc3);                               \
            acc0 = fmaf(a[j + 12], v3.x, acc0);                               \
            acc1 = fmaf(a[j + 13], v3.y, acc1);                               \
            acc2 = fmaf(a[j + 14], v3.z, acc2);                               \
            acc3 = fmaf(a[j + 15], v3.w, acc3);                               \
        }                                                                     \
        RES = xt_ * ((acc0 + acc1) + (acc2 + acc3));                          \
    } while (0)

__global__ __launch_bounds__(WPB * 64, 2)
void glv_rk4_kernel(const float* __restrict__ x0,
                    const float* __restrict__ r,
                    const float* __restrict__ A,
                    const float* __restrict__ tgrid,
                    float* __restrict__ out)
{
    const int lane = threadIdx.x & 63;
    const int wid  = threadIdx.x >> 6;
    const int b    = blockIdx.x * WPB + wid;   // batch element for this wave

    __shared__ float xs[WPB][2][D];            // per-wave stage-state buffers

    // Row `lane` of A into 64 registers (one-time; A is 16 KB, L2-resident).
    float a[D];
#pragma unroll
    for (int j = 0; j < D; j += 4) {
        const float4 v = *reinterpret_cast<const float4*>(A + lane * D + j);
        a[j + 0] = v.x; a[j + 1] = v.y; a[j + 2] = v.z; a[j + 3] = v.w;
    }
    // Anti-sink fence: volatile asm executes exactly once -> the 64 A-loads
    // cannot be sunk into / rematerialized inside the time loop.
#pragma unroll
    for (int j = 0; j < D; ++j)
        asm volatile("" : "+v"(a[j]));

    const float ri = r[lane];
    const float dt = tgrid[1] - tgrid[0];
    const float h2 = 0.5f * dt;
    const float h6 = dt * (1.0f / 6.0f);

    float x = x0[(size_t)b * D + lane];

    float* const buf0 = &xs[wid][0][0];
    float* const buf1 = &xs[wid][1][0];

    float* o = out + (size_t)b * NT * D + lane;
    *o = x; o += D;                            // t = 0 is x0

    for (int t = 1; t < NT; ++t) {
        float k1, k2, k3, k4;
        FEVAL(x, buf0, k1);
        FEVAL(fmaf(h2, k1, x), buf1, k2);
        FEVAL(fmaf(h2, k2, x), buf0, k3);
        FEVAL(fmaf(dt, k3, x), buf1, k4);
        x = fmaf(h6, (k1 + k4) + 2.0f * (k2 + k3), x);
        *o = x; o += D;                        // coalesced 256 B/wave store
    }
}

extern "C" void kernel_launch(void* const* d_in, const int* in_sizes, int n_in,
                              void* d_out, int out_size, void* d_ws, size_t ws_size,
                              hipStream_t stream) {
    const float* x0    = (const float*)d_in[0];
    const float* r     = (const float*)d_in[1];
    const float* A     = (const float*)d_in[2];
    const float* tgrid = (const float*)d_in[3];
    float* out         = (float*)d_out;

    const int batch = in_sizes[0] / D;          // 2048
    dim3 grid(batch / WPB);                     // 512 blocks
    dim3 block(WPB * 64);                       // 256 threads = 4 waves

    glv_rk4_kernel<<<grid, block, 0, stream>>>(x0, r, A, tgrid, out);
}

// Round 5
// 299.321 us; speedup vs baseline: 1.4721x; 1.3862x over previous
//
#include <hip/hip_runtime.h>

// Generalized Lotka-Volterra, RK4, D=64, batch 2048, 255 steps,
// trajectory out (batch, 256, 64) fp32.
//
// Mapping: one 64-lane wave per batch element; lane i owns component i.
// A is split as A = -I + E (E = A + I, all entries ~0.0025 scale).
// f(x) = x .* (r - x + E@x):  diagonal & r in exact fp32, E@x in packed f16
// v_dot2_f32_f16 (2 MACs/instr, fp32 accumulate). E lives in 32 VGPRs as
// packed f16 pairs (pinned against loop-sinking with volatile asm — rounds
// 1-3 showed the compiler otherwise re-fetches A every feval).
//
// Broadcast design (the round-4 lesson): any LDS-based broadcast replicates
// the x-vector into all 64 lanes = 16 KB LDS traffic per feval per wave
// -> 33 GB total -> ~480 us LDS-BW-bound floor. Instead: pack (x_{2J},
// x_{2J+1}) as f16x2 in 32 bits (cvt + DPP-xor1 + lshl_or), then 32
// v_readlane broadcasts -> SGPRs -> dot2 operands. Zero LDS, readlanes
// batched ahead of consumers so no VALU->SGPR hazard stalls.

constexpr int D   = 64;   // state dimension == wavefront size
constexpr int NT  = 256;  // trajectory length (255 RK4 steps)
constexpr int WPB = 4;    // waves (= batch elements) per block

typedef _Float16 half2v __attribute__((ext_vector_type(2)));

__device__ __forceinline__ float dot2_f16(uint32_t a, uint32_t b, float c) {
#if __has_builtin(__builtin_amdgcn_fdot2)
    return __builtin_amdgcn_fdot2(__builtin_bit_cast(half2v, a),
                                  __builtin_bit_cast(half2v, b), c, false);
#else
    float r = c;
    asm("v_dot2_f32_f16 %0, %1, %2, %0" : "+v"(r) : "v"(a), "v"(b));
    return r;
#endif
}

__device__ __forceinline__ uint32_t f16lo(float x) {
    return (uint32_t)__builtin_bit_cast(uint16_t, (_Float16)x);
}

// f(xt) = xt * (r - xt + E@xt), wave-cooperative via readlane broadcast.
#define FEVAL(XT, RES)                                                        \
    do {                                                                      \
        const float xt_ = (XT);                                               \
        const uint32_t hl = f16lo(xt_);                                       \
        const uint32_t nb = (uint32_t)__builtin_amdgcn_update_dpp(            \
            0, (int)hl, 0xB1 /*quad_perm [1,0,3,2] = xor1*/, 0xF, 0xF, true); \
        const uint32_t pair = hl | (nb << 16); /* valid on even lanes */      \
        uint32_t xs[D / 2];                                                   \
        _Pragma("unroll")                                                     \
        for (int J = 0; J < D / 2; ++J)                                       \
            xs[J] = (uint32_t)__builtin_amdgcn_readlane((int)pair, 2 * J);    \
        float a0 = ri, a1 = 0.f, a2 = 0.f, a3 = 0.f;                          \
        _Pragma("unroll")                                                     \
        for (int J = 0; J < D / 2; J += 4) {                                  \
            a0 = dot2_f16(e[J + 0], xs[J + 0], a0);                           \
            a1 = dot2_f16(e[J + 1], xs[J + 1], a1);                           \
            a2 = dot2_f16(e[J + 2], xs[J + 2], a2);                           \
            a3 = dot2_f16(e[J + 3], xs[J + 3], a3);                           \
        }                                                                     \
        RES = xt_ * (((a0 + a1) + (a2 + a3)) - xt_);                          \
    } while (0)

__global__ __launch_bounds__(WPB * 64, 2)
void glv_rk4_kernel(const float* __restrict__ x0,
                    const float* __restrict__ r,
                    const float* __restrict__ A,
                    const float* __restrict__ tgrid,
                    float* __restrict__ out)
{
    const int lane = threadIdx.x & 63;
    const int wid  = threadIdx.x >> 6;
    const int b    = blockIdx.x * WPB + wid;   // batch element for this wave

    // E = A + I, row `lane`, packed f16 pairs -> 32 VGPRs.
    uint32_t e[D / 2];
#pragma unroll
    for (int J = 0; J < D / 2; ++J) {
        const float e0 = A[lane * D + 2 * J]     + ((2 * J)     == lane ? 1.0f : 0.0f);
        const float e1 = A[lane * D + 2 * J + 1] + ((2 * J + 1) == lane ? 1.0f : 0.0f);
        e[J] = f16lo(e0) | (f16lo(e1) << 16);
    }
    // Anti-sink fence: volatile asm executes exactly once -> E cannot be
    // re-materialized inside the time loop (rounds 1-3 failure mode).
#pragma unroll
    for (int J = 0; J < D / 2; ++J)
        asm volatile("" : "+v"(e[J]));

    const float ri = r[lane];
    const float dt = tgrid[1] - tgrid[0];
    const float h2 = 0.5f * dt;
    const float h6 = dt * (1.0f / 6.0f);

    float x = x0[(size_t)b * D + lane];

    float* o = out + (size_t)b * NT * D + lane;
    *o = x; o += D;                            // t = 0 is x0

    for (int t = 1; t < NT; ++t) {
        float k1, k2, k3, k4;
        FEVAL(x, k1);
        FEVAL(fmaf(h2, k1, x), k2);
        FEVAL(fmaf(h2, k2, x), k3);
        FEVAL(fmaf(dt, k3, x), k4);
        x = fmaf(h6, (k1 + k4) + 2.0f * (k2 + k3), x);
        *o = x; o += D;                        // coalesced 256 B/wave store
    }
}

extern "C" void kernel_launch(void* const* d_in, const int* in_sizes, int n_in,
                              void* d_out, int out_size, void* d_ws, size_t ws_size,
                              hipStream_t stream) {
    const float* x0    = (const float*)d_in[0];
    const float* r     = (const float*)d_in[1];
    const float* A     = (const float*)d_in[2];
    const float* tgrid = (const float*)d_in[3];
    float* out         = (float*)d_out;

    const int batch = in_sizes[0] / D;          // 2048
    dim3 grid(batch / WPB);                     // 512 blocks
    dim3 block(WPB * 64);                       // 256 threads = 4 waves

    glv_rk4_kernel<<<grid, block, 0, stream>>>(x0, r, A, tgrid, out);
}